// Round 9
// baseline (1012.976 us; speedup 1.0000x reference)
//
#include <hip/hip_runtime.h>
#include <cstdint>

typedef _Float16 f16x8 __attribute__((ext_vector_type(8)));
typedef float f32x4 __attribute__((ext_vector_type(4)));

#define MDIM 24000   // N*T rows
#define DDIM 1024
#define CDIM 20
#define TDIM 750
#define NBATCH 32
#define KSEL 657
#define MASKV -100.0f
#define OMEGAF 0.6f
#define SPLIT_SCALE 2048.0f
#define SPLIT_INV   4.8828125e-4f   // 2^-11 exact

// d_out element offsets (x_r, cls_x_r, cls_x_ra, x_f, cls_x_f, cls_x_fa, tcam)
#define OFF_XR     0L
#define OFF_CLSX_R 24576000L
#define OFF_CLSRA  25056000L
#define OFF_XF     25536000L
#define OFF_CLSX_F 50112000L
#define OFF_CLSFA  50592000L
#define OFF_TCAM   51072000L

#define GLOAD16(g, l) __builtin_amdgcn_global_load_lds( \
    (const __attribute__((address_space(1))) void*)(g), \
    (__attribute__((address_space(3))) void*)(l), 16, 0, 0)

#define SBAR0() __builtin_amdgcn_sched_barrier(0)

// ---------------------------------------------------------------------------
// split helpers
// ---------------------------------------------------------------------------
__global__ __launch_bounds__(256)
void split_f16(const float* __restrict__ src, long srcStride, long nrows,
               _Float16* __restrict__ D0, _Float16* __restrict__ D1) {
    const long nvec = nrows * 128;
    for (long v = (long)blockIdx.x * 256 + threadIdx.x; v < nvec; v += (long)gridDim.x * 256) {
        const long row = v >> 7;
        const int c8 = (int)(v & 127) << 3;
        const float4 x0 = *reinterpret_cast<const float4*>(&src[row * srcStride + c8]);
        const float4 x1 = *reinterpret_cast<const float4*>(&src[row * srcStride + c8 + 4]);
        float xs[8] = {x0.x, x0.y, x0.z, x0.w, x1.x, x1.y, x1.z, x1.w};
        f16x8 h0, h1;
#pragma unroll
        for (int j = 0; j < 8; ++j) {
            const _Float16 a = (_Float16)xs[j];
            h0[j] = a;
            h1[j] = (_Float16)((xs[j] - (float)a) * SPLIT_SCALE);
        }
        *reinterpret_cast<f16x8*>(&D0[v << 3]) = h0;
        *reinterpret_cast<f16x8*>(&D1[v << 3]) = h1;
    }
}

// ---------------------------------------------------------------------------
// Fused-panel split-f16 GEMM, counted-vmcnt 2-deep pipeline.
//   accH += A0.B0 ; accL += A0.B1 + A1.B0 ; out = accH + 2^-11*accL.
// 128x128 tile, 256 thr = 4 waves (2x2), per-wave 64x64, BK=32.
// LDS: 2 buf x 4 tiles (A0,A1,B0,B1; 128x32 f16) = 64 KiB -> 2 blocks/CU.
// r9 restructure: accH (16 MFMA, depends only on av0/bv0) moved BEFORE
// lgkmcnt(0)/barrier B -- it runs inside the read-latency tail of the
// remaining 8 reads (free); accL (32 MFMA) stays after barrier B overlapping
// next STAGE8. setprio(1) wraps both MFMA clusters (T5; wave role-split
// regime now exists). All r8 sched_barrier pins kept verbatim: reads can't
// sink past the lgkmcnt(0) "memory" asm; STAGE8 can't hoist past the
// post-barrier-B SBAR0.
// ---------------------------------------------------------------------------
template<int MODE>
__global__ __launch_bounds__(256, 2)
void gemm_fused_f16(const _Float16* __restrict__ A0, const _Float16* __restrict__ A1,
                    const _Float16* __restrict__ B0, const _Float16* __restrict__ B1,
                    const float* __restrict__ bias,
                    float* __restrict__ outF,
                    _Float16* __restrict__ H0, _Float16* __restrict__ H1) {
    __shared__ _Float16 sm[32768];   // 2 x 16384 f16 (A0|A1|B0|B1 tiles)
    const int t = threadIdx.x;
    const int lane = t & 63;
    const int wave = t >> 6;
    const int wr = wave >> 1, wc = wave & 1;
    const int lr = lane & 15, lk = lane >> 4;
    const int wr4 = wr * 4, wc4 = wc * 4;

    // XCD-chunked, N-fastest: 1504 = 8 XCD chunks of 188; wg = m*8 + n
    const int bid = blockIdx.x;
    const int wg = (bid & 7) * 188 + (bid >> 3);
    const long bm = (long)(wg >> 3) * 128;
    const int bn = (wg & 7) * 128;

    // hoisted stage addressing (rows are loop-invariant; only k advances)
    const int r_in = lane >> 2;          // 0..15
    const int c8 = (lane & 3) << 3;      // 0,8,16,24 f16
    long ra0 = bm + (wave * 2 + 0) * 16 + r_in; if (ra0 > MDIM - 1) ra0 = MDIM - 1;
    long ra1 = bm + (wave * 2 + 1) * 16 + r_in; if (ra1 > MDIM - 1) ra1 = MDIM - 1;
    const long rb0 = (long)(bn + (wave * 2 + 0) * 16 + r_in);
    const long rb1 = (long)(bn + (wave * 2 + 1) * 16 + r_in);
    const _Float16* pA0a = A0 + (ra0 << 10) + c8;
    const _Float16* pA0b = A0 + (ra1 << 10) + c8;
    const _Float16* pA1a = A1 + (ra0 << 10) + c8;
    const _Float16* pA1b = A1 + (ra1 << 10) + c8;
    const _Float16* pB0a = B0 + (rb0 << 10) + c8;
    const _Float16* pB0b = B0 + (rb1 << 10) + c8;
    const _Float16* pB1a = B1 + (rb0 << 10) + c8;
    const _Float16* pB1b = B1 + (rb1 << 10) + c8;
    const int sb0 = (wave * 2 + 0) * 512 + lane * 8;
    const int sb1 = (wave * 2 + 1) * 512 + lane * 8;

#define STAGE8(par) do { \
    _Float16* _d = sm + (par) * 16384; \
    GLOAD16(pA0a, _d + sb0);         GLOAD16(pA0b, _d + sb1); \
    GLOAD16(pA1a, _d + 4096 + sb0);  GLOAD16(pA1b, _d + 4096 + sb1); \
    GLOAD16(pB0a, _d + 8192 + sb0);  GLOAD16(pB0b, _d + 8192 + sb1); \
    GLOAD16(pB1a, _d + 12288 + sb0); GLOAD16(pB1b, _d + 12288 + sb1); \
    pA0a += 32; pA0b += 32; pA1a += 32; pA1b += 32; \
    pB0a += 32; pB0b += 32; pB1a += 32; pB1b += 32; \
} while (0)

#define LDSF(tileoff, rb) (*(const f16x8*)&sm[cur + (tileoff) + (rb) * 512 + lr * 32 + lk * 8])

    f32x4 accH[4][4], accL[4][4];
#pragma unroll
    for (int mi = 0; mi < 4; ++mi)
#pragma unroll
        for (int ni = 0; ni < 4; ++ni) {
            accH[mi][ni] = (f32x4){0.f, 0.f, 0.f, 0.f};
            accL[mi][ni] = (f32x4){0.f, 0.f, 0.f, 0.f};
        }

    f16x8 av0[4], av1[4], bv0[4], bv1[4];

    // Phase 1 (between barrier A and barrier B): issue all 16 reads, run accH
    // (depends only on av0/bv0) inside the latency tail of av1/bv1, then
    // pin all reads retired before barrier B.
#define COMPUTE_P1() do { \
    SBAR0(); /* pin: reads stay AFTER barrier A */ \
    _Pragma("unroll") for (int mi = 0; mi < 4; ++mi) av0[mi] = LDSF(0,     wr4 + mi); \
    _Pragma("unroll") for (int ni = 0; ni < 4; ++ni) bv0[ni] = LDSF(8192,  wc4 + ni); \
    _Pragma("unroll") for (int mi = 0; mi < 4; ++mi) av1[mi] = LDSF(4096,  wr4 + mi); \
    _Pragma("unroll") for (int ni = 0; ni < 4; ++ni) bv1[ni] = LDSF(12288, wc4 + ni); \
    __builtin_amdgcn_s_setprio(1); \
    _Pragma("unroll") for (int mi = 0; mi < 4; ++mi) \
    _Pragma("unroll") for (int ni = 0; ni < 4; ++ni) \
        accH[mi][ni] = __builtin_amdgcn_mfma_f32_16x16x32_f16(av0[mi], bv0[ni], accH[mi][ni], 0, 0, 0); \
    __builtin_amdgcn_s_setprio(0); \
    asm volatile("s_waitcnt lgkmcnt(0)" ::: "memory"); \
    SBAR0(); \
} while (0)

    // Phase 2 (after barrier B): the 32 cross-term MFMAs, overlapping the
    // next STAGE8 issue + in-flight loads.
#define COMPUTE_P2() do { \
    SBAR0(); /* pin: MFMAs + next stage stay AFTER barrier B */ \
    __builtin_amdgcn_s_setprio(1); \
    _Pragma("unroll") for (int mi = 0; mi < 4; ++mi) \
    _Pragma("unroll") for (int ni = 0; ni < 4; ++ni) \
        accL[mi][ni] = __builtin_amdgcn_mfma_f32_16x16x32_f16(av0[mi], bv1[ni], accL[mi][ni], 0, 0, 0); \
    _Pragma("unroll") for (int mi = 0; mi < 4; ++mi) \
    _Pragma("unroll") for (int ni = 0; ni < 4; ++ni) \
        accL[mi][ni] = __builtin_amdgcn_mfma_f32_16x16x32_f16(av1[mi], bv0[ni], accL[mi][ni], 0, 0, 0); \
    __builtin_amdgcn_s_setprio(0); \
} while (0)

    STAGE8(0);                       // tile 0 -> buf0 (8 loads in flight)
    for (int step = 0; step < 31; ++step) {
        const int cur = (step & 1) * 16384;
        STAGE8((step + 1) & 1);      // tile t+1 (8 newest loads)
        SBAR0();                     // pin: stage issued before the wait
        asm volatile("s_waitcnt vmcnt(8)" ::: "memory");  // tile t landed
        SBAR0();
        __builtin_amdgcn_s_barrier();                     // A: cur buf ready
        COMPUTE_P1();
        __builtin_amdgcn_s_barrier();                     // B: cur buf consumed
        COMPUTE_P2();
    }
    {   // peeled last step: nothing left to stage, drain tile 31 fully
        const int cur = 16384;
        asm volatile("s_waitcnt vmcnt(0)" ::: "memory");
        SBAR0();
        __builtin_amdgcn_s_barrier();
        COMPUTE_P1();
        __builtin_amdgcn_s_barrier();
        COMPUTE_P2();
    }

    // epilogue: C/D layout col=lane&15, row=(lane>>4)*4+r (verified r2/r4/r5)
#pragma unroll
    for (int ni = 0; ni < 4; ++ni) {
        const int col = bn + wc * 64 + ni * 16 + lr;
        const float bb = bias[col];
#pragma unroll
        for (int mi = 0; mi < 4; ++mi) {
            const long rbase = bm + wr * 64 + mi * 16 + lk * 4;
#pragma unroll
            for (int r = 0; r < 4; ++r) {
                const long row = rbase + r;
                if (row < MDIM) {
                    const float v = accH[mi][ni][r] + SPLIT_INV * accL[mi][ni][r];
                    const float hv = fmaxf(v + bb, 0.f);
                    if (MODE == 0) {
                        const _Float16 h0 = (_Float16)hv;
                        H0[row * DDIM + col] = h0;
                        H1[row * DDIM + col] = (_Float16)((hv - (float)h0) * SPLIT_SCALE);
                    } else {
                        outF[row * DDIM + col] = hv;
                    }
                }
            }
        }
    }
#undef COMPUTE_P1
#undef COMPUTE_P2
#undef LDSF
#undef STAGE8
}

// ---------------------------------------------------------------------------
// cls/at heads in fp32 (precision-critical for the top-k mask), N padded to 48.
// M-tile 64 -> 376 blocks (fills 256 CUs better than 188).
// ---------------------------------------------------------------------------
__global__ __launch_bounds__(256)
void cls_gemm_f32(const float* __restrict__ H,
                  const float* __restrict__ Wc, const float* __restrict__ bc,
                  const float* __restrict__ Wa, const float* __restrict__ ba,
                  float* __restrict__ clsx, float* __restrict__ atout) {
    __shared__ float As[16][72];
    __shared__ float Bs[16][48];
    const int tid = threadIdx.x;
    const int tx = tid & 15, ty = tid >> 4;
    const long bm = (long)blockIdx.x * 64;

    float acc[4][3];
#pragma unroll
    for (int i = 0; i < 4; ++i)
#pragma unroll
        for (int j = 0; j < 3; ++j) acc[i][j] = 0.f;

    for (int k0 = 0; k0 < DDIM; k0 += 16) {
        __syncthreads();
        {
            const int row = tid >> 2;            // 0..63
            const int kc = (tid & 3) << 2;       // 0,4,8,12
            long ar = bm + row; if (ar > MDIM - 1) ar = MDIM - 1;
            const float4 va = *reinterpret_cast<const float4*>(&H[ar * DDIM + k0 + kc]);
            As[kc + 0][row] = va.x; As[kc + 1][row] = va.y;
            As[kc + 2][row] = va.z; As[kc + 3][row] = va.w;
        }
        if (tid < 192) {
            const int n = tid >> 2;
            const int kc = (tid & 3) << 2;
            float4 w = make_float4(0.f, 0.f, 0.f, 0.f);
            if (n < 20)      w = *reinterpret_cast<const float4*>(&Wc[(long)n * DDIM + k0 + kc]);
            else if (n < 40) w = *reinterpret_cast<const float4*>(&Wa[(long)(n - 20) * DDIM + k0 + kc]);
            Bs[kc + 0][n] = w.x; Bs[kc + 1][n] = w.y;
            Bs[kc + 2][n] = w.z; Bs[kc + 3][n] = w.w;
        }
        __syncthreads();
#pragma unroll
        for (int kk = 0; kk < 16; ++kk) {
            float a[4];
            *(float4*)&a[0] = *(const float4*)&As[kk][ty * 4];
            const float b0 = Bs[kk][tx];
            const float b1 = Bs[kk][tx + 16];
            const float b2 = Bs[kk][tx + 32];
#pragma unroll
            for (int i = 0; i < 4; ++i) {
                acc[i][0] = fmaf(a[i], b0, acc[i][0]);
                acc[i][1] = fmaf(a[i], b1, acc[i][1]);
                acc[i][2] = fmaf(a[i], b2, acc[i][2]);
            }
        }
    }

#pragma unroll
    for (int j = 0; j < 3; ++j) {
        const int col = tx + 16 * j;
        const bool isC = (col < 20);
        const bool isA = (col >= 20) && (col < 40);
        const float bvv = isC ? bc[col] : (isA ? ba[col - 20] : 0.f);
#pragma unroll
        for (int i = 0; i < 4; ++i) {
            const long row = bm + ty * 4 + i;
            if (row < MDIM) {
                const float v = acc[i][j] + bvv;
                if (isC)      clsx[row * CDIM + col] = v;
                else if (isA) atout[row * CDIM + col - 20] = v;
            }
        }
    }
}

// Per (stream,n,c): bitonic sort 750 values (pad to 1024 with +inf), emit rank KSEL.
__global__ __launch_bounds__(512)
void select_kth(const float* __restrict__ clsx_r, const float* __restrict__ clsx_f,
                float* __restrict__ kth) {
    __shared__ float s[1024];
    const int b = blockIdx.x;
    const int z = b / 640;
    const int rem = b - z * 640;
    const int n = rem / CDIM;
    const int c = rem - n * CDIM;
    const float* src = (z == 0) ? clsx_r : clsx_f;
    const int tid = threadIdx.x;

    for (int i = tid; i < 1024; i += 512)
        s[i] = (i < TDIM) ? src[((long)n * TDIM + i) * CDIM + c] : 3.402823466e38f;
    __syncthreads();

    for (int k = 2; k <= 1024; k <<= 1) {
        for (int j = k >> 1; j > 0; j >>= 1) {
            for (int i = tid; i < 1024; i += 512) {
                const int ixj = i ^ j;
                if (ixj > i) {
                    const bool up = ((i & k) == 0);
                    const float x = s[i], y = s[ixj];
                    if ((x > y) == up) { s[i] = y; s[ixj] = x; }
                }
            }
            __syncthreads();
        }
    }
    if (tid == 0) kth[b] = s[KSEL - 1];
}

__global__ __launch_bounds__(256)
void final_mask(float* __restrict__ out, const float* __restrict__ kth,
                const float* __restrict__ mul_r, const float* __restrict__ mul_f) {
    const int idx = blockIdx.x * 256 + threadIdx.x;
    if (idx >= NBATCH * TDIM * CDIM) return;
    const int m = idx / CDIM;
    const int c = idx - m * CDIM;
    const int n = m / TDIM;
    const float xr  = out[OFF_CLSX_R + idx];
    const float xf  = out[OFF_CLSX_F + idx];
    const float atr = out[OFF_CLSRA + idx];
    const float atf = out[OFF_CLSFA + idx];
    const float kr = kth[n * CDIM + c];
    const float kf = kth[640 + n * CDIM + c];
    out[OFF_CLSRA + idx] = (xr > kr) ? MASKV : atr;
    out[OFF_CLSFA + idx] = (xf > kf) ? MASKV : atf;
    out[OFF_TCAM + idx]  = (xr + OMEGAF * atr) * mul_r[c] + (xf + OMEGAF * atf) * mul_f[c];
}

extern "C" void kernel_launch(void* const* d_in, const int* in_sizes, int n_in,
                              void* d_out, int out_size, void* d_ws, size_t ws_size,
                              hipStream_t stream) {
    const float* inp    = (const float*)d_in[0];
    const float* Wfc_r  = (const float*)d_in[1];
    const float* bfc_r  = (const float*)d_in[2];
    const float* Wfc1_r = (const float*)d_in[3];
    const float* bfc1_r = (const float*)d_in[4];
    const float* Wfc_f  = (const float*)d_in[5];
    const float* bfc_f  = (const float*)d_in[6];
    const float* Wfc1_f = (const float*)d_in[7];
    const float* bfc1_f = (const float*)d_in[8];
    const float* Wcls_r = (const float*)d_in[9];
    const float* bcls_r = (const float*)d_in[10];
    const float* Wcls_f = (const float*)d_in[11];
    const float* bcls_f = (const float*)d_in[12];
    const float* Wra    = (const float*)d_in[13];
    const float* bra    = (const float*)d_in[14];
    const float* Wfa    = (const float*)d_in[15];
    const float* bfa    = (const float*)d_in[16];
    const float* mul_r  = (const float*)d_in[17];
    const float* mul_f  = (const float*)d_in[18];

    float* out = (float*)d_out;
    _Float16* wsA0 = (_Float16*)d_ws;           // 24000x1024 each
    _Float16* wsA1 = wsA0 + 24576000L;
    _Float16* wsH0 = wsA1 + 24576000L;
    _Float16* wsH1 = wsH0 + 24576000L;
    _Float16* wsW  = wsH1 + 24576000L;          // 8 x 1024x1024 f16
    float* kth = (float*)(wsW + 8L * 1048576L); // 1280 f32

    dim3 blk(256);
    dim3 gg(1504);

    split_f16<<<dim3(512), blk, 0, stream>>>(Wfc_r,  1024, 1024, wsW + 0L * 1048576, wsW + 1L * 1048576);
    split_f16<<<dim3(512), blk, 0, stream>>>(Wfc1_r, 1024, 1024, wsW + 2L * 1048576, wsW + 3L * 1048576);
    split_f16<<<dim3(512), blk, 0, stream>>>(Wfc_f,  1024, 1024, wsW + 4L * 1048576, wsW + 5L * 1048576);
    split_f16<<<dim3(512), blk, 0, stream>>>(Wfc1_f, 1024, 1024, wsW + 6L * 1048576, wsW + 7L * 1048576);

    // ---- RGB stream ----
    split_f16<<<dim3(2048), blk, 0, stream>>>(inp, 2 * DDIM, MDIM, wsA0, wsA1);
    gemm_fused_f16<0><<<gg, blk, 0, stream>>>(wsA0, wsA1, wsW + 0L * 1048576, wsW + 1L * 1048576,
                                              bfc_r, nullptr, wsH0, wsH1);
    gemm_fused_f16<1><<<gg, blk, 0, stream>>>(wsH0, wsH1, wsW + 2L * 1048576, wsW + 3L * 1048576,
                                              bfc1_r, out + OFF_XR, nullptr, nullptr);
    cls_gemm_f32<<<dim3(376), blk, 0, stream>>>(out + OFF_XR, Wcls_r, bcls_r, Wra, bra,
                                                out + OFF_CLSX_R, out + OFF_CLSRA);

    // ---- Flow stream ----
    split_f16<<<dim3(2048), blk, 0, stream>>>(inp + DDIM, 2 * DDIM, MDIM, wsA0, wsA1);
    gemm_fused_f16<0><<<gg, blk, 0, stream>>>(wsA0, wsA1, wsW + 4L * 1048576, wsW + 5L * 1048576,
                                              bfc_f, nullptr, wsH0, wsH1);
    gemm_fused_f16<1><<<gg, blk, 0, stream>>>(wsH0, wsH1, wsW + 6L * 1048576, wsW + 7L * 1048576,
                                              bfc1_f, out + OFF_XF, nullptr, nullptr);
    cls_gemm_f32<<<dim3(376), blk, 0, stream>>>(out + OFF_XF, Wcls_f, bcls_f, Wfa, bfa,
                                                out + OFF_CLSX_F, out + OFF_CLSFA);

    select_kth<<<dim3(1280), dim3(512), 0, stream>>>(out + OFF_CLSX_R, out + OFF_CLSX_F, kth);
    final_mask<<<dim3((NBATCH * TDIM * CDIM + 255) / 256), blk, 0, stream>>>(out, kth, mul_r, mul_f);
}